// Round 10
// baseline (127.721 us; speedup 1.0000x reference)
//
#include <hip/hip_runtime.h>
#include <math.h>

#define EPS 1e-8f
#define MAGIC 0x1F2E3D4C
typedef float f32x4 __attribute__((ext_vector_type(4)));

__device__ __forceinline__ float wredsum(float v) {
#pragma unroll
  for (int o = 32; o > 0; o >>= 1) v += __shfl_down(v, o, 64);
  return v;  // valid in lane 0
}

__device__ __forceinline__ void waitflag(const int* f) {
  while (__hip_atomic_load(f, __ATOMIC_RELAXED, __HIP_MEMORY_SCOPE_AGENT) !=
         MAGIC)
    __builtin_amdgcn_s_sleep(2);
}

// 8 consecutive k-steps of a 4-col FMA: c += x[k] * w[k][0..3]
__device__ __forceinline__ void fma8(const float4* w, const float4 a,
                                     const float4 b, float4& c) {
  const float xs[8] = {a.x, a.y, a.z, a.w, b.x, b.y, b.z, b.w};
#pragma unroll
  for (int i = 0; i < 8; ++i) {
    c.x = fmaf(xs[i], w[i].x, c.x);
    c.y = fmaf(xs[i], w[i].y, c.y);
    c.z = fmaf(xs[i], w[i].z, c.z);
    c.w = fmaf(xs[i], w[i].w, c.w);
  }
}

// ---------------- ONE kernel: 528 blocks x 256 -------------------------------
// Blocks 0..511: EXACT R4 layer-1 block (bit-identical p1: same fma chains,
//   same [11][32][36] LDS reduce, same 32-term serial sum). Flag fA[b].
// Blocks 512..527 (j): tail, R8 arithmetic orders preserved exactly.
//   W2 regs pre-issued BEFORE the fA wait (overlaps l1 execution).
//   Phase A -> p2[j], fB[j]. j<12: L3-prefetch finale weights, exit.
//   j>=12: stage-2 enc k-quarter q=j-12 (W3 pre-issued before fB wait), fC[q].
//   j==15: finale (sim + integrator), then RESETS all flags to 0 (robust to
//   repeated launches without workspace refill; 0 != MAGIC != poison).
__global__ __launch_bounds__(256, 2) void k_all(
    const float* __restrict__ xn, const float* __restrict__ xe,
    const float* __restrict__ W1, const float* __restrict__ b1,
    const float* __restrict__ W2, const float* __restrict__ b2,
    const float* __restrict__ W3, const float* __restrict__ b3,
    const float* __restrict__ mm,
    const float* __restrict__ Wi1, const float* __restrict__ bi1,
    const float* __restrict__ Wi2, const float* __restrict__ bi2,
    const float* __restrict__ Wi3, const float* __restrict__ bi3,
    float* __restrict__ p1, float* __restrict__ p2, float* __restrict__ encp,
    int* __restrict__ fA, int* __restrict__ fB, int* __restrict__ fC,
    float* __restrict__ out) {
  __shared__ __align__(16) float smem[12672];  // 50688 B union -> 3 blocks/CU
  const int t = threadIdx.x;
  const int b = blockIdx.x;

  if (b < 512) {
    // ================= LAYER 1: exact R4 block =================
    const int bx = b & 15, by = b >> 4;
    const int cg = t & 7, ks = t >> 3;
    const int col = bx * 32 + cg * 4;
    const int k0  = by * 256 + ks * 8;

    float4 w[8];
#pragma unroll
    for (int i = 0; i < 8; ++i)
      w[i] = *(const float4*)&W1[(size_t)(k0 + i) * 512 + col];

    float4 acc[11];
#pragma unroll
    for (int r = 0; r < 11; ++r) acc[r] = make_float4(0.f, 0.f, 0.f, 0.f);
    {
      const float4 a = *(const float4*)&xn[k0];
      const float4 bb = *(const float4*)&xn[k0 + 4];
      fma8(w, a, bb, acc[0]);
    }
#pragma unroll
    for (int r = 0; r < 10; ++r) {
      const float4 a = *(const float4*)&xe[r * 8192 + k0];
      const float4 bb = *(const float4*)&xe[r * 8192 + k0 + 4];
      fma8(w, a, bb, acc[r + 1]);
    }

    float* red = smem;  // [11][32][36]
#pragma unroll
    for (int r = 0; r < 11; ++r)
      *(float4*)&red[(r * 32 + ks) * 36 + cg * 4] = acc[r];
    __syncthreads();

    for (int o = t; o < 352; o += 256) {
      const int r = o >> 5, c = o & 31;
      float s = 0.f;
#pragma unroll
      for (int k = 0; k < 32; ++k) s += red[(r * 32 + k) * 36 + c];
      p1[((size_t)by * 11 + r) * 512 + bx * 32 + c] = s;
    }
    __syncthreads();  // drain p1 stores
    if (t == 0) {
      __threadfence();  // agent release
      __hip_atomic_store(&fA[b], MAGIC, __ATOMIC_RELAXED,
                         __HIP_MEMORY_SCOPE_AGENT);
    }
    return;
  }

  // ======================== TAIL (16 blocks) ================================
  const int j = b - 512;
  const int c = t;  // one W2/H2 column per thread

  // Pre-issue W2 rows [32j,32j+32) col c into regs — overlaps l1 execution.
  float w2r[32];
#pragma unroll
  for (int i = 0; i < 32; ++i)
    w2r[i] = W2[(size_t)(j * 32 + i) * 256 + c];

  // Wait for the 32 producer blocks of col-tile j (b = j + 16m).
  if (t < 32) waitflag(&fA[j + 16 * t]);
  __syncthreads();
  if (t == 0) __threadfence();  // acquire
  __syncthreads();

  // ---- Phase A: H1 cols [32j,32j+32) + H2 partial -> p2[j] (R8 order) ----
  float* h1s = smem;  // [11][32]
  for (int o = t; o < 352; o += 256) {
    const int r = o >> 5, cc = o & 31;
    const int col = j * 32 + cc;
    float s = b1[col];
#pragma unroll
    for (int ch = 0; ch < 32; ++ch) s += p1[(size_t)(ch * 11 + r) * 512 + col];
    h1s[r * 32 + cc] = fmaxf(s, 0.f);
  }
  __syncthreads();
  float* redA = smem + 1024;  // [4][11][256]
#pragma unroll
  for (int kg = 0; kg < 4; ++kg) {
    float acc[11];
#pragma unroll
    for (int r = 0; r < 11; ++r) acc[r] = 0.f;
#pragma unroll
    for (int kk = 0; kk < 8; ++kk) {
      const int kl = kg * 8 + kk;
#pragma unroll
      for (int r = 0; r < 11; ++r)
        acc[r] = fmaf(h1s[r * 32 + kl], w2r[kg * 8 + kk], acc[r]);
    }
#pragma unroll
    for (int r = 0; r < 11; ++r) redA[(kg * 11 + r) * 256 + c] = acc[r];
  }
  __syncthreads();
  for (int o = t; o < 2816; o += 256) {
    const int r = o >> 8, cc = o & 255;
    p2[(size_t)j * 2816 + o] = redA[r * 256 + cc] + redA[(11 + r) * 256 + cc] +
                               redA[(22 + r) * 256 + cc] +
                               redA[(33 + r) * 256 + cc];
  }
  __syncthreads();  // drain p2 stores
  if (t == 0) {
    __threadfence();
    __hip_atomic_store(&fB[j], MAGIC, __ATOMIC_RELAXED,
                       __HIP_MEMORY_SCOPE_AGENT);
  }

  if (j < 12) {
    // ---- L3 prefetch for the finale (die-shared L3); then exit ----
    float dead = 0.f;
    const int g = j * 256 + t;  // 3072 slots > 2720 needed
    if (g < 2144)      dead += ((const f32x4*)Wi1)[g][0];
    else if (g < 2656) dead += ((const f32x4*)Wi2)[g - 2144][0];
    else if (g < 2672) dead += ((const f32x4*)bi1)[g - 2656][0];
    else if (g < 2704) dead += ((const f32x4*)b3)[g - 2672][0];
    else if (g < 2712) dead += ((const f32x4*)bi2)[g - 2704][0];
    else if (g < 2720) dead += ((const f32x4*)Wi3)[g - 2712][0];
    asm volatile("" ::"v"(dead));
    return;
  }
  const int q = j - 12;  // 0..3: enc k-quarter [64q, 64q+64)

  // Pre-issue W3 k-quarter regs BEFORE the fB wait (cold fetch overlaps it).
  const int c3 = t & 127, half = t >> 7;
  float w3r[32];
#pragma unroll
  for (int i = 0; i < 32; ++i)
    w3r[i] = W3[(size_t)(q * 64 + half * 32 + i) * 128 + c3];

  if (t < 16) waitflag(&fB[t]);
  __syncthreads();
  if (t == 0) __threadfence();  // acquire: all 16 p2 slices visible
  __syncthreads();

  // ---- Stage 2: H2 k-quarter + enc partial -> encp[q] (R8 order) ----
  float* h2q = smem;  // [11][64]
  for (int o = t; o < 704; o += 256) {
    const int r = o >> 6, kk = o & 63;
    const int col = q * 64 + kk;
    float s = b2[col];
#pragma unroll
    for (int jj = 0; jj < 16; ++jj) s += p2[(size_t)jj * 2816 + r * 256 + col];
    h2q[r * 64 + kk] = fmaxf(s, 0.f);
  }
  __syncthreads();
  float* redB = smem + 1024;  // [8][11][128]
#pragma unroll
  for (int m = 0; m < 4; ++m) {
    const int kg3 = half * 4 + m;
    float acc[11];
#pragma unroll
    for (int r = 0; r < 11; ++r) acc[r] = 0.f;
#pragma unroll
    for (int kk = 0; kk < 8; ++kk) {
      const int kl = kg3 * 8 + kk;
#pragma unroll
      for (int r = 0; r < 11; ++r)
        acc[r] = fmaf(h2q[r * 64 + kl], w3r[m * 8 + kk], acc[r]);
    }
#pragma unroll
    for (int r = 0; r < 11; ++r) redB[(kg3 * 11 + r) * 128 + c3] = acc[r];
  }
  __syncthreads();
  for (int o = t; o < 1408; o += 256) {
    const int r = o >> 7, cc = o & 127;
    float s = 0.f;
#pragma unroll
    for (int g = 0; g < 8; ++g) s += redB[(g * 11 + r) * 128 + cc];
    encp[(size_t)q * 1408 + o] = s;
  }
  __syncthreads();  // drain encp stores
  if (t == 0) {
    __threadfence();
    __hip_atomic_store(&fC[q], MAGIC, __ATOMIC_RELAXED,
                       __HIP_MEMORY_SCOPE_AGENT);
  }
  if (j != 15) return;

  // ---- Finale (block 527): wait fC, stage Wi, similarity + integrator ----
  if (t < 4) waitflag(&fC[t]);
  __syncthreads();
  if (t == 0) __threadfence();  // acquire: all 4 encp slices visible
  __syncthreads();

  float* encs = smem;           // 1408
  float* wi1s = smem + 1536;    // 8576
  float* wi2s = smem + 10112;   // 2048
  float* comb = smem + 12160;   // 134
  float* h1b  = smem + 12296;   // 64
  for (int i = t; i < 2144; i += 256)
    ((f32x4*)wi1s)[i] = ((const f32x4*)Wi1)[i];
  for (int i = t; i < 512; i += 256)
    ((f32x4*)wi2s)[i] = ((const f32x4*)Wi2)[i];
  for (int o = t; o < 1408; o += 256) {
    float s = b3[o & 127];
#pragma unroll
    for (int g = 0; g < 4; ++g) s += encp[(size_t)g * 1408 + o];
    encs[o] = s;  // encoder outputs incl. bias; row 0 = new_knowledge
  }
  __syncthreads();

  float consist = 0.f;
  float n0 = 0.f, n1 = 0.f;
  if (t < 64) {
    n0 = encs[t]; n1 = encs[64 + t];
    comb[t] = n0; comb[64 + t] = n1;
    if (t < 6) comb[128 + t] = mm[t];
  }
  __syncthreads();  // comb ready
  if (t < 64) {
    // wave 0: similarity (concurrent with wave 1's MLP layer 1)
    const float nn = wredsum(n0 * n0 + n1 * n1);
#pragma unroll
    for (int r = 1; r <= 10; ++r) {
      const float e0 = encs[r * 128 + t];
      const float e1 = encs[r * 128 + 64 + t];
      const float d0 = e0 - n0, d1 = e1 - n1;
      const float g  = wredsum(d0 * d0 + d1 * d1);
      const float qq = wredsum(e0 * e0 + e1 * e1);
      const float dd = wredsum(e0 * n0 + e1 * n1);
      if (t == 0) {
        const float geo = sqrtf(g);
        const float den = fmaxf(sqrtf(nn), EPS) * fmaxf(sqrtf(qq), EPS);
        consist += geo - dd / den;
      }
    }
  } else if (t < 128) {
    // wave 1: integrator layer 1 (Wi1 from LDS)
    const int tt = t - 64;
    float hh = bi1[tt];
#pragma unroll 4
    for (int k = 0; k < 134; ++k) hh = fmaf(comb[k], wi1s[k * 64 + tt], hh);
    h1b[tt] = fmaxf(hh, 0.f);
  }
  __syncthreads();
  if (t < 64) {
    float part = 0.f;
    if (t < 32) {
      float hh = bi2[t];
#pragma unroll 8
      for (int k = 0; k < 64; ++k) hh = fmaf(h1b[k], wi2s[k * 32 + t], hh);
      part = fmaxf(hh, 0.f) * Wi3[t];
    }
    const float qual = wredsum(part);
    if (t == 0) out[0] = consist * 0.1f + expf(-(qual + bi3[0]));
  }

  // ---- Reset all flags (everyone has consumed; robust to no-refill relaunch)
  __syncthreads();
  for (int i = t; i < 512; i += 256)
    __hip_atomic_store(&fA[i], 0, __ATOMIC_RELAXED, __HIP_MEMORY_SCOPE_AGENT);
  if (t < 16)
    __hip_atomic_store(&fB[t], 0, __ATOMIC_RELAXED, __HIP_MEMORY_SCOPE_AGENT);
  if (t < 4)
    __hip_atomic_store(&fC[t], 0, __ATOMIC_RELAXED, __HIP_MEMORY_SCOPE_AGENT);
}

extern "C" void kernel_launch(void* const* d_in, const int* in_sizes, int n_in,
                              void* d_out, int out_size, void* d_ws, size_t ws_size,
                              hipStream_t stream) {
  (void)in_sizes; (void)n_in; (void)out_size; (void)ws_size;
  const float* xn  = (const float*)d_in[0];
  const float* xe  = (const float*)d_in[1];
  const float* mm  = (const float*)d_in[2];
  const float* W1  = (const float*)d_in[3];
  const float* b1  = (const float*)d_in[4];
  const float* W2  = (const float*)d_in[5];
  const float* b2  = (const float*)d_in[6];
  const float* W3  = (const float*)d_in[7];
  const float* b3  = (const float*)d_in[8];
  const float* Wi1 = (const float*)d_in[9];
  const float* bi1 = (const float*)d_in[10];
  const float* Wi2 = (const float*)d_in[11];
  const float* bi2 = (const float*)d_in[12];
  const float* Wi3 = (const float*)d_in[13];
  const float* bi3 = (const float*)d_in[14];
  float* out = (float*)d_out;

  char* ws = (char*)d_ws;
  float* p1   = (float*)(ws);            // 32*11*512*4 = 720896 B
  float* p2   = (float*)(ws + 720896);   // 16*11*256*4 = 180224 B
  float* encp = (float*)(ws + 901120);   // 4*11*128*4  =  22528 B
  int*   fA   = (int*)  (ws + 923648);   // 512 ints
  int*   fB   = (int*)  (ws + 925696);   // 16 ints
  int*   fC   = (int*)  (ws + 925760);   // 4 ints

  hipLaunchKernelGGL(k_all, dim3(528), dim3(256), 0, stream,
                     xn, xe, W1, b1, W2, b2, W3, b3, mm,
                     Wi1, bi1, Wi2, bi2, Wi3, bi3,
                     p1, p2, encp, fA, fB, fC, out);
}

// Round 11
// 110.680 us; speedup vs baseline: 1.1540x; 1.1540x over previous
//
#include <hip/hip_runtime.h>
#include <math.h>

#define EPS 1e-8f
#define MAGIC 0x1F2E3D4C
typedef float f32x4 __attribute__((ext_vector_type(4)));

__device__ __forceinline__ float wredsum(float v) {
#pragma unroll
  for (int o = 32; o > 0; o >>= 1) v += __shfl_down(v, o, 64);
  return v;  // valid in lane 0
}

__device__ __forceinline__ void waitflag(const int* f) {
  while (__hip_atomic_load(f, __ATOMIC_RELAXED, __HIP_MEMORY_SCOPE_AGENT) !=
         MAGIC)
    __builtin_amdgcn_s_sleep(2);
}

// 8 consecutive k-steps of a 4-col FMA: c += x[k] * w[k][0..3]
__device__ __forceinline__ void fma8(const float4* w, const float4 a,
                                     const float4 b, float4& c) {
  const float xs[8] = {a.x, a.y, a.z, a.w, b.x, b.y, b.z, b.w};
#pragma unroll
  for (int i = 0; i < 8; ++i) {
    c.x = fmaf(xs[i], w[i].x, c.x);
    c.y = fmaf(xs[i], w[i].y, c.y);
    c.z = fmaf(xs[i], w[i].z, c.z);
    c.w = fmaf(xs[i], w[i].w, c.w);
  }
}

// ---------------- Layer 1: EXACT R4 block (bit-exact p1) + flag zeroing ------
__global__ __launch_bounds__(256, 2) void k_l1(const float* __restrict__ xn,
                                               const float* __restrict__ xe,
                                               const float* __restrict__ W1,
                                               float* __restrict__ p1,
                                               int* __restrict__ flg) {
  if (blockIdx.x == 0 && blockIdx.y == 0 && threadIdx.x < 40)
    flg[threadIdx.x] = 0;  // kernel boundary orders this before k_tail reads
  __shared__ float red[11 * 32 * 36];  // 50688 B
  const int cg  = threadIdx.x & 7;
  const int ks  = threadIdx.x >> 3;
  const int col = blockIdx.x * 32 + cg * 4;
  const int k0  = blockIdx.y * 256 + ks * 8;

  float4 w[8];
#pragma unroll
  for (int i = 0; i < 8; ++i)
    w[i] = *(const float4*)&W1[(size_t)(k0 + i) * 512 + col];

  float4 acc[11];
#pragma unroll
  for (int r = 0; r < 11; ++r) acc[r] = make_float4(0.f, 0.f, 0.f, 0.f);
  {
    const float4 a = *(const float4*)&xn[k0];
    const float4 b = *(const float4*)&xn[k0 + 4];
    fma8(w, a, b, acc[0]);
  }
#pragma unroll
  for (int r = 0; r < 10; ++r) {
    const float4 a = *(const float4*)&xe[r * 8192 + k0];
    const float4 b = *(const float4*)&xe[r * 8192 + k0 + 4];
    fma8(w, a, b, acc[r + 1]);
  }

#pragma unroll
  for (int r = 0; r < 11; ++r)
    *(float4*)&red[(r * 32 + ks) * 36 + cg * 4] = acc[r];
  __syncthreads();

  for (int o = threadIdx.x; o < 352; o += 256) {
    const int r = o >> 5, c = o & 31;
    float s = 0.f;
#pragma unroll
    for (int k = 0; k < 32; ++k) s += red[(r * 32 + k) * 36 + c];
    p1[((size_t)blockIdx.y * 11 + r) * 512 + blockIdx.x * 32 + c] = s;
  }
}

// ---------------- Tail: 41 blocks x 256, fixed roles, 2 flag hops ------------
// j<32  (phase A): H1 cols [16j,16j+16) + H2 partial (1 col/thread, no LDS
//        reduce) -> p2 grouped by consumer [q][j]; flag fB[j]=flg[j].
// j<40  (stage 2, q=j-32): W3 regs pre-issued BEFORE fB wait; finish H2 for
//        H2-cols [32q,32q+32); enc k-partial -> encp[q]; flag fC=flg[32+q].
// j==40 (finale): stages Wi1/Wi2 -> LDS at kernel START (overlaps A+2!),
//        waits fC, enc sum + similarity + integrator.
// 41 blocks <= 256 CUs -> co-resident -> spins deadlock-free.
__global__ __launch_bounds__(256) void k_tail(
    const float* __restrict__ p1, const float* __restrict__ b1,
    const float* __restrict__ W2, const float* __restrict__ b2,
    const float* __restrict__ W3, const float* __restrict__ b3,
    const float* __restrict__ mm,
    const float* __restrict__ Wi1, const float* __restrict__ bi1,
    const float* __restrict__ Wi2, const float* __restrict__ bi2,
    const float* __restrict__ Wi3, const float* __restrict__ bi3,
    float* __restrict__ p2, float* __restrict__ encp,
    int* __restrict__ flg, float* __restrict__ out) {
  __shared__ __align__(16) float smem[12672];
  const int t = threadIdx.x;
  const int j = blockIdx.x;

  if (j < 32) {
    // ---- Phase A ----
    float w2r[16];  // W2 rows [16j,16j+16), col t — 16 KB/block, coalesced
#pragma unroll
    for (int i = 0; i < 16; ++i)
      w2r[i] = W2[(size_t)(j * 16 + i) * 256 + t];

    float* h1s = smem;  // [11][16]
    if (t < 176) {
      const int r = t >> 4, cc = t & 15;
      const int col = j * 16 + cc;
      float s = b1[col];
#pragma unroll
      for (int ch = 0; ch < 32; ++ch)
        s += p1[(size_t)(ch * 11 + r) * 512 + col];
      h1s[r * 16 + cc] = fmaxf(s, 0.f);
    }
    __syncthreads();

    float acc[11];
#pragma unroll
    for (int r = 0; r < 11; ++r) acc[r] = 0.f;
#pragma unroll
    for (int kk = 0; kk < 16; ++kk) {
#pragma unroll
      for (int r = 0; r < 11; ++r)
        acc[r] = fmaf(h1s[r * 16 + kk], w2r[kk], acc[r]);
    }
    // p2 grouped by consumer: [q=col>>5][j][r][col&31]
    const int q = t >> 5, cc = t & 31;
#pragma unroll
    for (int r = 0; r < 11; ++r)
      p2[((size_t)q * 32 + j) * 352 + r * 32 + cc] = acc[r];

    __syncthreads();  // drain p2 stores
    if (t == 0) {
      __threadfence();  // agent release
      __hip_atomic_store(&flg[j], MAGIC, __ATOMIC_RELAXED,
                         __HIP_MEMORY_SCOPE_AGENT);
    }
    return;
  }

  if (j < 40) {
    // ---- Stage 2 (q = j-32): enc k-partial for H2-cols [32q,32q+32) ----
    const int q = j - 32;
    const int c3 = t & 127, half = t >> 7;
    float w3r[16];  // pre-issued BEFORE the wait: cold fetch overlaps it
#pragma unroll
    for (int i = 0; i < 16; ++i)
      w3r[i] = W3[(size_t)(q * 32 + half * 16 + i) * 128 + c3];

    if (t < 32) waitflag(&flg[t]);
    __syncthreads();
    if (t == 0) __threadfence();  // acquire: all 32 p2 slices visible
    __syncthreads();

    float* h2q = smem;  // [11][32]
    for (int o = t; o < 352; o += 256) {
      const int r = o >> 5, kk = o & 31;
      float s = b2[q * 32 + kk];
#pragma unroll
      for (int jj = 0; jj < 32; ++jj)
        s += p2[((size_t)q * 32 + jj) * 352 + r * 32 + kk];
      h2q[r * 32 + kk] = fmaxf(s, 0.f);
    }
    __syncthreads();

    float* redB = smem + 512;  // [2][11][128]
    {
      float acc[11];
#pragma unroll
      for (int r = 0; r < 11; ++r) acc[r] = 0.f;
#pragma unroll
      for (int i = 0; i < 16; ++i) {
        const int kk = half * 16 + i;
#pragma unroll
        for (int r = 0; r < 11; ++r)
          acc[r] = fmaf(h2q[r * 32 + kk], w3r[i], acc[r]);
      }
#pragma unroll
      for (int r = 0; r < 11; ++r) redB[(half * 11 + r) * 128 + c3] = acc[r];
    }
    __syncthreads();
    for (int o = t; o < 1408; o += 256)
      encp[(size_t)q * 1408 + o] = redB[o] + redB[1408 + o];

    __syncthreads();  // drain encp stores
    if (t == 0) {
      __threadfence();
      __hip_atomic_store(&flg[32 + q], MAGIC, __ATOMIC_RELAXED,
                         __HIP_MEMORY_SCOPE_AGENT);
    }
    return;
  }

  // ---- Finale (block 40) ----
  float* encs = smem;            // 1408
  float* wi1s = smem + 1536;     // 8576
  float* wi2s = smem + 10112;    // 2048
  float* comb = smem + 12160;    // 134
  float* h1b  = smem + 12296;    // 64
  // Stage Wi1/Wi2 NOW — inputs, independent of flags; overlaps phases A+2.
  for (int i = t; i < 2144; i += 256)
    ((f32x4*)wi1s)[i] = ((const f32x4*)Wi1)[i];
  for (int i = t; i < 512; i += 256)
    ((f32x4*)wi2s)[i] = ((const f32x4*)Wi2)[i];

  if (t < 8) waitflag(&flg[32 + t]);
  __syncthreads();
  if (t == 0) __threadfence();  // acquire: all 8 encp slices visible
  __syncthreads();

  for (int o = t; o < 1408; o += 256) {
    float s = b3[o & 127];
#pragma unroll
    for (int g = 0; g < 8; ++g) s += encp[(size_t)g * 1408 + o];
    encs[o] = s;  // encoder outputs incl. bias; row 0 = new_knowledge
  }
  __syncthreads();

  float consist = 0.f;
  float n0 = 0.f, n1 = 0.f;
  if (t < 64) {
    n0 = encs[t]; n1 = encs[64 + t];
    comb[t] = n0; comb[64 + t] = n1;
    if (t < 6) comb[128 + t] = mm[t];
  }
  __syncthreads();  // comb ready
  if (t < 64) {
    // wave 0: similarity (concurrent with wave 1's MLP layer 1)
    const float nn = wredsum(n0 * n0 + n1 * n1);
#pragma unroll
    for (int r = 1; r <= 10; ++r) {
      const float e0 = encs[r * 128 + t];
      const float e1 = encs[r * 128 + 64 + t];
      const float d0 = e0 - n0, d1 = e1 - n1;
      const float g  = wredsum(d0 * d0 + d1 * d1);
      const float qq = wredsum(e0 * e0 + e1 * e1);
      const float dd = wredsum(e0 * n0 + e1 * n1);
      if (t == 0) {
        const float geo = sqrtf(g);
        const float den = fmaxf(sqrtf(nn), EPS) * fmaxf(sqrtf(qq), EPS);
        consist += geo - dd / den;
      }
    }
  } else if (t < 128) {
    // wave 1: integrator layer 1 (Wi1 from LDS)
    const int tt = t - 64;
    float hh = bi1[tt];
#pragma unroll 4
    for (int k = 0; k < 134; ++k) hh = fmaf(comb[k], wi1s[k * 64 + tt], hh);
    h1b[tt] = fmaxf(hh, 0.f);
  }
  __syncthreads();
  if (t < 64) {
    float part = 0.f;
    if (t < 32) {
      float hh = bi2[t];
#pragma unroll 8
      for (int k = 0; k < 64; ++k) hh = fmaf(h1b[k], wi2s[k * 32 + t], hh);
      part = fmaxf(hh, 0.f) * Wi3[t];
    }
    const float qual = wredsum(part);
    if (t == 0) out[0] = consist * 0.1f + expf(-(qual + bi3[0]));
  }
}

extern "C" void kernel_launch(void* const* d_in, const int* in_sizes, int n_in,
                              void* d_out, int out_size, void* d_ws, size_t ws_size,
                              hipStream_t stream) {
  (void)in_sizes; (void)n_in; (void)out_size; (void)ws_size;
  const float* xn  = (const float*)d_in[0];
  const float* xe  = (const float*)d_in[1];
  const float* mm  = (const float*)d_in[2];
  const float* W1  = (const float*)d_in[3];
  const float* b1  = (const float*)d_in[4];
  const float* W2  = (const float*)d_in[5];
  const float* b2  = (const float*)d_in[6];
  const float* W3  = (const float*)d_in[7];
  const float* b3  = (const float*)d_in[8];
  const float* Wi1 = (const float*)d_in[9];
  const float* bi1 = (const float*)d_in[10];
  const float* Wi2 = (const float*)d_in[11];
  const float* bi2 = (const float*)d_in[12];
  const float* Wi3 = (const float*)d_in[13];
  const float* bi3 = (const float*)d_in[14];
  float* out = (float*)d_out;

  char* ws = (char*)d_ws;
  float* p1   = (float*)(ws);             // 32*11*512*4      = 720896 B
  float* p2   = (float*)(ws + 720896);    // 8*32*352*4       = 360448 B
  float* encp = (float*)(ws + 1081344);   // 8*1408*4         =  45056 B
  int*   flg  = (int*)  (ws + 1126400);   // 40 ints

  hipLaunchKernelGGL(k_l1,   dim3(16, 32), dim3(256), 0, stream,
                     xn, xe, W1, p1, flg);
  hipLaunchKernelGGL(k_tail, dim3(41),     dim3(256), 0, stream,
                     p1, b1, W2, b2, W3, b3, mm,
                     Wi1, bi1, Wi2, bi2, Wi3, bi3, p2, encp, flg, out);
}